// Round 20
// baseline (121.181 us; speedup 1.0000x reference)
//
#include <hip/hip_runtime.h>

// ============================================================================
// AttentionWithSpatial: x@Wqkv -> masked/biased 4-head attention -> @Wout+b
// b=4, n=2048, dim=256, heads=4, dhead=64, scale=0.125
//
// R19 post-mortem: compiler re-fused the load/convert loops (VGPR 40 -> only
// ~4 loads in flight -> Little's law 1.6 TB/s, matches). R20: force load
// batching with __builtin_amdgcn_sched_barrier(0) between the load loop and
// the convert loop (nothing may cross) -> all 16 loads issued + live.
// All kernels otherwise byte-identical to passing R19.
// ============================================================================

#define B_   4
#define N_   2048
#define H_   4
#define DH_  64
#define DIMX 256
#define M_   (B_*N_)   // 8192

#define LOG2E  1.4426950408889634f
#define NEGINF (-1e30f)
#define DEFER_THR 8.0f

typedef __attribute__((ext_vector_type(8))) short short8;
typedef __attribute__((ext_vector_type(4))) float f32x4;
typedef unsigned short u16;
typedef unsigned int   u32;

#define MFMA16(a,b,c) __builtin_amdgcn_mfma_f32_16x16x32_bf16((a),(b),(c),0,0,0)

__device__ __forceinline__ u16 f2bf(float f) {
  u32 u = __builtin_bit_cast(u32, f);
  u += 0x7fffu + ((u >> 16) & 1u);   // RNE
  return (u16)(u >> 16);
}
__device__ __forceinline__ float bf2f(u16 h) {
  u32 u = ((u32)h) << 16;
  return __builtin_bit_cast(float, u);
}
__device__ __forceinline__ void split2(float f, u16* hi, u16* lo) {
  u16 h = f2bf(f);
  *hi = h;
  *lo = f2bf(f - bf2f(h));
}
__device__ __forceinline__ u32 cvtpk(float lo, float hi) {
  u32 r;
  asm("v_cvt_pk_bf16_f32 %0, %1, %2" : "=v"(r) : "v"(lo), "v"(hi));
  return r;
}
__device__ __forceinline__ u16 f2h(float f) {
  return __builtin_bit_cast(u16, (_Float16)f);
}

struct u16v4 { u16 a, b, c, d; };
struct u16v8 { u16 v[8]; };

// ---------------------------------------------------------------------------
// Kernel 1 (prep):
//  blocks [0,2048): bias prefuse via LDS transpose. Loads forced into one
//    batch (sched_barrier(0) fence) -> 16 loads in flight per thread.
//  blocks [2048,5120): x -> xh/xl split; Wqkv/Wout transpose+split.
// ---------------------------------------------------------------------------
__global__ __launch_bounds__(256) void k_prep(
    const int* __restrict__ mask, const float* __restrict__ spat,
    const float* __restrict__ x, const float* __restrict__ wq,
    const float* __restrict__ wo,
    u16* __restrict__ biasF,
    u16* __restrict__ xh, u16* __restrict__ xl,
    u16* __restrict__ wqh, u16* __restrict__ wql,
    u16* __restrict__ woh, u16* __restrict__ wol)
{
  __shared__ __align__(16) u16 LB[8192];   // 16 KB fp16 tile

  const int tid = threadIdx.x;
  if (blockIdx.x < 2048) {
    const int blk = blockIdx.x;
    const int ch = blk & 3;              // 512-col chunk
    const int qt = (blk >> 2) & 127;
    const int b  = blk >> 9;
    const float NB = -10000.0f;

    // ---- batched loads: ALL 16 issued before the fence ----
    int4   m[8];
    float4 s[8];
#pragma unroll
    for (int rep = 0; rep < 8; ++rep) {
      const int i4 = rep * 256 + tid;            // [0, 2048)
      const int row = i4 >> 7;                   // [0,16)
      const int colc = i4 & 127;                 // int4 within row
      const int gidx = (b * N_ + qt * 16 + row) * N_ + ch * 512 + colc * 4;
      m[rep] = *(const int4*)&mask[gidx];
      s[rep] = *(const float4*)&spat[gidx];
    }
    __builtin_amdgcn_sched_barrier(0);   // nothing crosses: loads stay batched

    // ---- convert + dense LDS stores ----
#pragma unroll
    for (int rep = 0; rep < 8; ++rep) {
      const int i4 = rep * 256 + tid;
      const int row = i4 >> 7;
      const int colc = i4 & 127;
      u32 w0 = (u32)f2h(m[rep].x ? s[rep].x * LOG2E : NB)
             | ((u32)f2h(m[rep].y ? s[rep].y * LOG2E : NB) << 16);
      u32 w1 = (u32)f2h(m[rep].z ? s[rep].z * LOG2E : NB)
             | ((u32)f2h(m[rep].w ? s[rep].w * LOG2E : NB) << 16);
      const int ktl = colc >> 3, j = (colc >> 2) & 1, hb = colc & 3;
      const int A = (row * 1024 + ktl * 64 + hb * 16 + j * 8)
                  ^ ((row & 1) << 6);            // byte offset, 8B-aligned
      uint2 wv; wv.x = w0; wv.y = w1;
      *(uint2*)&LB[A >> 1] = wv;
    }
    __syncthreads();

    // ---- writer: 4 records/thread, b128 LDS gather + coalesced store ----
    const size_t rbase = ((size_t)(b * 128 + qt) * 64 + ch * 16) * 64;
#pragma unroll
    for (int rep = 0; rep < 4; ++rep) {
      const int o = rep * 256 + tid;             // [0, 1024)
      const int ktl = o >> 6, lane2 = o & 63;
      const int ln2 = lane2 & 15, hb2 = lane2 >> 4;
      const int A = (ln2 * 1024 + ktl * 64 + hb2 * 16) ^ ((ln2 & 1) << 6);
      const short8 v = *(const short8*)&LB[A >> 1];
      *(short8*)&biasF[(rbase + o) * 8] = v;
    }
    return;
  }

  const int NX4 = (M_ * DIMX) / 4;  // 524288
  const int NWQ = 768 * 256;        // 196608
  const int NWO = 256 * 256;        // 65536
  int i = (blockIdx.x - 2048) * 256 + tid;
  if (i < NX4) {
    const float4 v = ((const float4*)x)[i];
    u16v4 hv, lv;
    split2(v.x, &hv.a, &lv.a);
    split2(v.y, &hv.b, &lv.b);
    split2(v.z, &hv.c, &lv.c);
    split2(v.w, &hv.d, &lv.d);
    ((u16v4*)xh)[i] = hv;
    ((u16v4*)xl)[i] = lv;
  } else if (i < NX4 + NWQ) {
    int j = i - NX4;
    int c = j >> 8, k = j & 255;            // out layout [c][k]
    split2(wq[k * 768 + c], &wqh[j], &wql[j]);
  } else if (i < NX4 + NWQ + NWO) {
    int j = i - NX4 - NWQ;
    int c = j >> 8, k = j & 255;
    split2(wo[k * 256 + c], &woh[j], &wol[j]);
  }
}

// ---------------------------------------------------------------------------
// Kernel 2: QKV GEMM, LDS-staged. M=8192, N=768, K=256. grid (12, 64).
// B tile (hi+lo) staged once in 64KB LDS, XOR-swizzled; 2 M-subtiles/block;
// 16 A loads upfront per subtile; MFMA fed from LDS.
// ---------------------------------------------------------------------------
__global__ __launch_bounds__(256) void k_qkv(
    const u16* __restrict__ xh, const u16* __restrict__ xl,
    const u16* __restrict__ wh, const u16* __restrict__ wl,
    u16* __restrict__ qh, u16* __restrict__ ql,
    u16* __restrict__ kf, u16* __restrict__ vf)
{
  __shared__ __align__(16) u16 BhL[64 * 256];   // 32 KB, swizzled
  __shared__ __align__(16) u16 BlL[64 * 256];   // 32 KB

  const int tid = threadIdx.x;
  const int w = tid >> 6, lane = tid & 63;
  const int ln = lane & 15, hb = lane >> 4;
  const int colb = blockIdx.x * 64;

  // ---- stage B (hi+lo) into LDS, reg-batched, coalesced ----
  {
    short8 sb[16];
#pragma unroll
    for (int it = 0; it < 8; ++it) {
      const int c = it * 8 + (tid >> 5), k8 = tid & 31;
      sb[it]     = *(const short8*)&wh[(colb + c) * 256 + k8 * 8];
      sb[8 + it] = *(const short8*)&wl[(colb + c) * 256 + k8 * 8];
    }
#pragma unroll
    for (int it = 0; it < 8; ++it) {
      const int c = it * 8 + (tid >> 5), k8 = tid & 31;
      const int le = c * 256 + ((k8 * 8) ^ ((c & 7) << 3));
      *(short8*)&BhL[le] = sb[it];
      *(short8*)&BlL[le] = sb[8 + it];
    }
  }
  __syncthreads();

#pragma unroll
  for (int st = 0; st < 2; ++st) {
    const int mtile = blockIdx.y * 2 + st;
    const int arow = mtile * 64 + w * 16 + ln;

    short8 a_h8[8], a_l8[8];
#pragma unroll
    for (int ks = 0; ks < 8; ++ks) {
      a_h8[ks] = *(const short8*)&xh[arow * 256 + ks * 32 + hb * 8];
      a_l8[ks] = *(const short8*)&xl[arow * 256 + ks * 32 + hb * 8];
    }

    f32x4 acc[4] = {};
#pragma unroll
    for (int ks = 0; ks < 8; ++ks) {
      const int k0 = ks * 32 + hb * 8;
#pragma unroll
      for (int j = 0; j < 4; ++j) {
        const int c = j * 16 + ln;
        const int le = c * 256 + (k0 ^ ((c & 7) << 3));
        const short8 b_h = *(const short8*)&BhL[le];
        const short8 b_l = *(const short8*)&BlL[le];
        acc[j] = MFMA16(a_h8[ks], b_h, acc[j]);
        acc[j] = MFMA16(a_l8[ks], b_h, acc[j]);
        acc[j] = MFMA16(a_h8[ks], b_l, acc[j]);
      }
    }

    const int mbase = mtile * 64 + w * 16 + hb * 4;
#pragma unroll
    for (int j = 0; j < 4; ++j) {
      const int c = colb + j * 16 + ln;
      const int which = c >> 8;        // 0=q 1=k 2=v
      const int hd = c & 255;
      const int hh = hd >> 6, d = hd & 63;
#pragma unroll
      for (int r = 0; r < 4; ++r) {
        const int m = mbase + r;
        const int bb = m >> 11, nn = m & 2047;
        const int bh = bb * H_ + hh;
        float v = acc[j][r];
        if (which == 0) {
          const int off = (bh * N_ + nn) * DH_ + d;
          v *= (0.125f * LOG2E);                 // scale + exp2-domain fold
          split2(v, &qh[off], &ql[off]);
        } else if (which == 1) {
          const int ktile = nn >> 5, jj = (nn >> 4) & 1, lnn = nn & 15;
          const int kc = d >> 5, hbb = (d >> 3) & 3, e = d & 7;
          const int off = (bh * 64 + ktile) * 2048 + (kc * 2 + jj) * 512
                        + (hbb * 16 + lnn) * 8 + e;
          kf[off] = f2bf(v);
        } else {
          const int ktile = nn >> 5, hbb = (nn >> 3) & 3, e = nn & 7;
          const int j2 = d >> 4, lnn = d & 15;
          const int off = (bh * 64 + ktile) * 2048 + j2 * 512
                        + (hbb * 16 + lnn) * 8 + e;
          vf[off] = f2bf(v);
        }
      }
    }
  }
}

// ---------------------------------------------------------------------------
// Kernel 3: flash attention partials, KV-split=2, BARRIER-FREE (R12 verbatim,
// best measured 54.4us). grid 1024: bid -> half=bid&1, bh=(bid>>1)&15,
// qq=bid>>5. 4 waves = 4 q-tiles of SAME (b,h,half): K/V fragments read
// per-wave directly from global (4x redundancy L1-absorbed). K reg-dbuf one
// tile ahead; V issue-early/use-late; bias fp16 acc-init. Swapped PV:
// O[d][q], q=ln lane-local rescale/l. LDS = per-wave Pbuf only.
// ---------------------------------------------------------------------------
__global__ __launch_bounds__(256, 4) void k_attn(
    const u16* __restrict__ qhg, const u16* __restrict__ qlg,
    const u16* __restrict__ kfg, const u16* __restrict__ vfg,
    const u16* __restrict__ biasF,
    float* __restrict__ Op0, float* __restrict__ Op1,
    float* __restrict__ MP, float* __restrict__ LP)
{
  __shared__ __align__(16) u32 Pbuf[4][320];   // 5 KB: per-wave P exchange

  const int bid = blockIdx.x;
  const int half = bid & 1;
  const int bh = (bid >> 1) & 15;
  const int qq = bid >> 5;
  const int b = bh >> 2, h = bh & 3;
  const int kt0 = half * 32;

  const int tid = threadIdx.x;
  const int w = tid >> 6, lane = tid & 63;
  const int qt = qq * 4 + w;                   // this wave's q-tile [0,128)
  const int ln = lane & 15, hb = lane >> 4;

  // ---- Q fragments (pre-scaled by 0.125*log2e), hi/lo ----
  short8 qfh[2], qfl[2];
  {
    const int base = ((b * H_ + h) * N_ + qt * 16 + ln) * DH_;
    qfh[0] = *(const short8*)&qhg[base + hb * 8];
    qfh[1] = *(const short8*)&qhg[base + 32 + hb * 8];
    qfl[0] = *(const short8*)&qlg[base + hb * 8];
    qfl[1] = *(const short8*)&qlg[base + 32 + hb * 8];
  }

  // per-lane fragment bases (lane*8 folded in; per-tile offset = kt*2048)
  const u16* Kt0 = kfg + (size_t)((b * H_ + h) * 64) * 2048 + lane * 8;
  const u16* Vt0 = vfg + (size_t)((b * H_ + h) * 64) * 2048 + lane * 8;
  const u16* Bt0 = biasF + (size_t)((b * 128 + qt) * 64) * 512 + lane * 8;

  short8 ones;
#pragma unroll
  for (int i = 0; i < 8; ++i) ones[i] = (short)0x3F80;   // bf16 1.0

  f32x4 O[4] = {};        // lane holds O[d=j2*16+hb*4+r][q=ln]
  f32x4 l_acc = {};       // all entries = l(q=ln)
  float m_run = NEGINF;   // per-lane (q=ln)
  u32* Pw = &Pbuf[w][0];

  short8 Ka[4], Kb[4], bc, bn;

  // ---- prologue: K tile kt0 + bias kt0 ----
#pragma unroll
  for (int i = 0; i < 4; ++i)
    Ka[i] = *(const short8*)&Kt0[kt0 * 2048 + i * 512];
  bc = *(const short8*)&Bt0[kt0 * 512];

  auto body = [&](short8 (&Kc)[4], short8 (&Kn)[4],
                  short8& bcur, short8& bnxt, int ktc, int ktn) {
    // ---- issue loads: V for THIS tile (used late), K+bias for NEXT ----
    short8 Vc[4];
#pragma unroll
    for (int i = 0; i < 4; ++i)
      Vc[i] = *(const short8*)&Vt0[ktc * 2048 + i * 512];
#pragma unroll
    for (int i = 0; i < 4; ++i)
      Kn[i] = *(const short8*)&Kt0[ktn * 2048 + i * 512];
    bnxt = *(const short8*)&Bt0[ktn * 512];

    // ---- swapped QK^T, accumulator init = bias ----
    f32x4 dots[2];
#pragma unroll
    for (int j = 0; j < 2; ++j)
#pragma unroll
      for (int r = 0; r < 4; ++r)
        dots[j][r] = (float)__builtin_bit_cast(_Float16, (u16)bcur[j * 4 + r]);
    __builtin_amdgcn_s_setprio(1);
#pragma unroll
    for (int kc = 0; kc < 2; ++kc)
#pragma unroll
      for (int j = 0; j < 2; ++j) {
        dots[j] = MFMA16(Kc[kc * 2 + j], qfh[kc], dots[j]);
        dots[j] = MFMA16(Kc[kc * 2 + j], qfl[kc], dots[j]);
      }
    __builtin_amdgcn_s_setprio(0);

    // ---- per-q online softmax (q=ln), defer-max THR=8 ----
    float pmax = fmaxf(fmaxf(fmaxf(dots[0][0], dots[0][1]),
                             fmaxf(dots[0][2], dots[0][3])),
                       fmaxf(fmaxf(dots[1][0], dots[1][1]),
                             fmaxf(dots[1][2], dots[1][3])));
    pmax = fmaxf(pmax, __shfl_xor(pmax, 16));
    pmax = fmaxf(pmax, __shfl_xor(pmax, 32));
    if (__any(pmax > m_run + DEFER_THR)) {
      const float mn = fmaxf(m_run, pmax);
      const float fac = exp2f(m_run - mn);     // lane-local (q=ln)
      m_run = mn;
#pragma unroll
      for (int j2 = 0; j2 < 4; ++j2) {
        O[j2][0] *= fac; O[j2][1] *= fac; O[j2][2] *= fac; O[j2][3] *= fac;
      }
      l_acc[0] *= fac; l_acc[1] *= fac; l_acc[2] *= fac; l_acc[3] *= fac;
    }
    float p[2][4];
#pragma unroll
    for (int j = 0; j < 2; ++j)
#pragma unroll
      for (int r = 0; r < 4; ++r)
        p[j][r] = exp2f(dots[j][r] - m_run);

    // ---- P-exchange via per-wave LDS (wave-synchronous, no barrier) ----
#pragma unroll
    for (int j = 0; j < 2; ++j) {
      uint2 wv;
      wv.x = cvtpk(p[j][0], p[j][1]);
      wv.y = cvtpk(p[j][2], p[j][3]);
      *(uint2*)&Pw[ln * 20 + j * 8 + hb * 2] = wv;   // k = j*16+hb*4+{0..3}
    }
    const short8 pf = *(const short8*)&Pw[ln * 20 + hb * 4];

    // ---- swapped PV: O += V^T_A x P_B ; l += ones x P ----
    __builtin_amdgcn_s_setprio(1);
#pragma unroll
    for (int j2 = 0; j2 < 4; ++j2)
      O[j2] = MFMA16(Vc[j2], pf, O[j2]);
    l_acc = MFMA16(ones, pf, l_acc);
    __builtin_amdgcn_s_setprio(0);
  };

  for (int it = 0; it < 16; ++it) {
    const int t  = kt0 + 2 * it;
    const int t2 = kt0 + ((2 * it + 2) & 31);  // wraps on last prefetch
    body(Ka, Kb, bc, bn, t,     t + 1);
    body(Kb, Ka, bn, bc, t + 1, t2);
  }

  // ---- epilogue: write unnormalized partial O + per-q m,l ----
  const int gg = (b * H_ + h) * 128 + qt;          // [0, 2048)
  const int g  = gg * 2 + half;                    // MP/LP index
  float* Opg = (half ? Op1 : Op0) + (size_t)gg * 1024;
#pragma unroll
  for (int j2 = 0; j2 < 4; ++j2)
    *(f32x4*)&Opg[ln * 64 + j2 * 16 + hb * 4] = O[j2];
  if (hb == 0) {
    MP[g * 16 + ln] = m_run;
    LP[g * 16 + ln] = l_acc[0];
  }
}

// ---------------------------------------------------------------------------
// Kernel 4 (fused comb+out): out = merge(Op0,Op1;MP,LP) @ Wout + b_out.
// grid (4,64): colb = bx*64; 2 M-subtiles/block; B hi+lo in 64KB LDS.
// A-fragments: merged = (Op0*f1 + Op1*f2)/l per head, split bf16 in-register.
// ---------------------------------------------------------------------------
__global__ __launch_bounds__(256) void k_out(
    const float* __restrict__ Op0, const float* __restrict__ Op1,
    const float* __restrict__ MP, const float* __restrict__ LP,
    const u16* __restrict__ wh, const u16* __restrict__ wl,
    const float* __restrict__ bout, float* __restrict__ out)
{
  __shared__ __align__(16) u16 BhL[64 * 256];   // 32 KB, swizzled
  __shared__ __align__(16) u16 BlL[64 * 256];   // 32 KB

  const int tid = threadIdx.x;
  const int w = tid >> 6, lane = tid & 63;
  const int ln = lane & 15, hb = lane >> 4;
  const int colb = blockIdx.x * 64;

  // ---- stage B (hi+lo) into LDS ----
  {
    short8 sb[16];
#pragma unroll
    for (int it = 0; it < 8; ++it) {
      const int c = it * 8 + (tid >> 5), k8 = tid & 31;
      sb[it]     = *(const short8*)&wh[(colb + c) * 256 + k8 * 8];
      sb[8 + it] = *(const short8*)&wl[(colb + c) * 256 + k8 * 8];
    }
#pragma unroll
    for (int it = 0; it < 8; ++it) {
      const int c = it * 8 + (tid >> 5), k8 = tid & 31;
      const int le = c * 256 + ((k8 * 8) ^ ((c & 7) << 3));
      *(short8*)&BhL[le] = sb[it];
      *(short8*)&BlL[le] = sb[8 + it];
    }
  }
  __syncthreads();

#pragma unroll
  for (int st = 0; st < 2; ++st) {
    const int mtile = blockIdx.y * 2 + st;
    const int arow = mtile * 64 + w * 16 + ln;
    const int bb = arow >> 11, nn = arow & 2047;
    const int qt = nn >> 4, q = nn & 15;

    // ---- per-head merge factors (fo1 = f1/l, fo2 = f2/l) ----
    float fo1[4], fo2[4];
    int ggh[4];
#pragma unroll
    for (int hh = 0; hh < 4; ++hh) {
      const int gg = (bb * H_ + hh) * 128 + qt;
      ggh[hh] = gg;
      const float m1 = MP[gg * 32 + q],      m2 = MP[gg * 32 + 16 + q];
      const float l1 = LP[gg * 32 + q],      l2 = LP[gg * 32 + 16 + q];
      const float mm = fmaxf(m1, m2);
      const float f1 = exp2f(m1 - mm), f2 = exp2f(m2 - mm);
      const float inv = 1.0f / (l1 * f1 + l2 * f2);
      fo1[hh] = f1 * inv;
      fo2[hh] = f2 * inv;
    }

    // ---- build merged A-fragments (bf16 hi/lo) from Op0/Op1 ----
    short8 a_h8[8], a_l8[8];
#pragma unroll
    for (int ks = 0; ks < 8; ++ks) {
      const int hh = ks >> 1;                    // head of this k-chunk
      const int d0 = (ks & 1) * 32 + hb * 8;
      const size_t base = (size_t)ggh[hh] * 1024 + q * 64 + d0;
      const f32x4 u0 = *(const f32x4*)&Op0[base];
      const f32x4 u1 = *(const f32x4*)&Op0[base + 4];
      const f32x4 v0 = *(const f32x4*)&Op1[base];
      const f32x4 v1 = *(const f32x4*)&Op1[base + 4];
#pragma unroll
      for (int e = 0; e < 4; ++e) {
        const float mv = u0[e] * fo1[hh] + v0[e] * fo2[hh];
        const u16 hbits = f2bf(mv);
        a_h8[ks][e] = (short)hbits;
        a_l8[ks][e] = (short)f2bf(mv - bf2f(hbits));
      }
#pragma unroll
      for (int e = 0; e < 4; ++e) {
        const float mv = u1[e] * fo1[hh] + v1[e] * fo2[hh];
        const u16 hbits = f2bf(mv);
        a_h8[ks][e + 4] = (short)hbits;
        a_l8[ks][e + 4] = (short)f2bf(mv - bf2f(hbits));
      }
    }

    f32x4 acc[4] = {};
#pragma unroll
    for (int ks = 0; ks < 8; ++ks) {
      const int k0 = ks * 32 + hb * 8;
#pragma unroll
      for (int j = 0; j < 4; ++j) {
        const int c = j * 16 + ln;
        const int le = c * 256 + (k0 ^ ((c & 7) << 3));
        const short8 b_h = *(const short8*)&BhL[le];
        const short8 b_l = *(const short8*)&BlL[le];
        acc[j] = MFMA16(a_h8[ks], b_h, acc[j]);
        acc[j] = MFMA16(a_l8[ks], b_h, acc[j]);
        acc[j] = MFMA16(a_h8[ks], b_l, acc[j]);
      }
    }

    const int mbase = mtile * 64 + w * 16 + hb * 4;
#pragma unroll
    for (int j = 0; j < 4; ++j) {
      const int c = colb + j * 16 + ln;
      const float bbv = bout[c];
#pragma unroll
      for (int r = 0; r < 4; ++r)
        out[(mbase + r) * 256 + c] = acc[j][r] + bbv;
    }
  }
}

// ---------------------------------------------------------------------------
extern "C" void kernel_launch(void* const* d_in, const int* in_sizes, int n_in,
                              void* d_out, int out_size, void* d_ws, size_t ws_size,
                              hipStream_t stream)
{
  (void)in_sizes; (void)n_in; (void)out_size; (void)ws_size;
  const float* x    = (const float*)d_in[0];
  const int*   mask = (const int*)d_in[1];
  const float* spat = (const float*)d_in[2];
  const float* wq   = (const float*)d_in[3];
  const float* wo   = (const float*)d_in[4];
  const float* bout = (const float*)d_in[5];
  float* out = (float*)d_out;

  char* ws = (char*)d_ws;
  size_t o = 0;
  auto alloc = [&](size_t bytes) -> char* {
    char* p = ws + o;
    o += (bytes + 255) & ~(size_t)255;
    return p;
  };
  u16* xh  = (u16*)alloc((size_t)M_ * 256 * 2);   // 4 MB  \ Op0 alias (8 MB)
  u16* xl  = (u16*)alloc((size_t)M_ * 256 * 2);   // 4 MB  /
  u16* wqh = (u16*)alloc((size_t)768 * 256 * 2);  // 384KB -> MP alias (256KB)
  u16* wql = (u16*)alloc((size_t)768 * 256 * 2);  // 384KB -> LP alias (256KB)
  u16* woh = (u16*)alloc((size_t)256 * 256 * 2);
  u16* wol = (u16*)alloc((size_t)256 * 256 * 2);
  u16* qh  = (u16*)alloc((size_t)16 * N_ * DH_ * 2);
  u16* ql  = (u16*)alloc((size_t)16 * N_ * DH_ * 2);
  u16* kf  = (u16*)alloc((size_t)16 * N_ * DH_ * 2);
  u16* vf  = (u16*)alloc((size_t)16 * N_ * DH_ * 2);
  u16* biasF = (u16*)alloc((size_t)4 * 128 * 64 * 512 * 2);  // 33.5 MB fp16
  float* Op1 = (float*)alloc((size_t)2048 * 1024 * 4);       // 8 MB fresh

  // Aliases (dead by the time they're written, R9-proven pattern):
  //  Op0 (8,388,608 B) <- xh+xl (contiguous, dead after k_qkv)
  //  MP/LP (262,144 B) <- wqh / wql (393,216 B each, dead after k_qkv)
  float* Op0 = (float*)xh;
  float* MP  = (float*)wqh;
  float* LP  = (float*)wql;

  hipLaunchKernelGGL(k_prep, dim3(5120), dim3(256), 0, stream,
                     mask, spat, x, wq, wo, biasF,
                     xh, xl, wqh, wql, woh, wol);
  hipLaunchKernelGGL(k_qkv, dim3(12, 64), dim3(256), 0, stream,
                     xh, xl, wqh, wql, qh, ql, kf, vf);
  hipLaunchKernelGGL(k_attn, dim3(1024), dim3(256), 0, stream,
                     qh, ql, kf, vf, biasF, Op0, Op1, MP, LP);
  hipLaunchKernelGGL(k_out, dim3(4, 64), dim3(256), 0, stream,
                     Op0, Op1, MP, LP, woh, wol, bout, out);
}

// Round 21
// 119.972 us; speedup vs baseline: 1.0101x; 1.0101x over previous
//
#include <hip/hip_runtime.h>

// ============================================================================
// AttentionWithSpatial: x@Wqkv -> masked/biased 4-head attention -> @Wout+b
// b=4, n=2048, dim=256, heads=4, dhead=64, scale=0.125
//
// R20 post-mortem: sched_barrier(0) is MIS-level only; loads were re-fused
// with uses at IR level (VGPR 36 -> 2-4 loads in flight -> ~2 TB/s).
// R21: IR-proof fence -- ONE asm volatile keep-alive consuming a component
// of all 16 loaded vectors between load loop and convert loop (loads must
// precede their consumer at every compiler level). VGPR should jump >=80.
// All kernels otherwise byte-identical to passing R20.
// ============================================================================

#define B_   4
#define N_   2048
#define H_   4
#define DH_  64
#define DIMX 256
#define M_   (B_*N_)   // 8192

#define LOG2E  1.4426950408889634f
#define NEGINF (-1e30f)
#define DEFER_THR 8.0f

typedef __attribute__((ext_vector_type(8))) short short8;
typedef __attribute__((ext_vector_type(4))) float f32x4;
typedef unsigned short u16;
typedef unsigned int   u32;

#define MFMA16(a,b,c) __builtin_amdgcn_mfma_f32_16x16x32_bf16((a),(b),(c),0,0,0)

__device__ __forceinline__ u16 f2bf(float f) {
  u32 u = __builtin_bit_cast(u32, f);
  u += 0x7fffu + ((u >> 16) & 1u);   // RNE
  return (u16)(u >> 16);
}
__device__ __forceinline__ float bf2f(u16 h) {
  u32 u = ((u32)h) << 16;
  return __builtin_bit_cast(float, u);
}
__device__ __forceinline__ void split2(float f, u16* hi, u16* lo) {
  u16 h = f2bf(f);
  *hi = h;
  *lo = f2bf(f - bf2f(h));
}
__device__ __forceinline__ u32 cvtpk(float lo, float hi) {
  u32 r;
  asm("v_cvt_pk_bf16_f32 %0, %1, %2" : "=v"(r) : "v"(lo), "v"(hi));
  return r;
}
__device__ __forceinline__ u16 f2h(float f) {
  return __builtin_bit_cast(u16, (_Float16)f);
}

struct u16v4 { u16 a, b, c, d; };
struct u16v8 { u16 v[8]; };

// ---------------------------------------------------------------------------
// Kernel 1 (prep):
//  blocks [0,2048): bias prefuse via LDS transpose; 16 loads forced in
//    flight by a single asm keep-alive fence (IR-level, cannot be sunk).
//  blocks [2048,5120): x -> xh/xl split; Wqkv/Wout transpose+split.
// ---------------------------------------------------------------------------
__global__ __launch_bounds__(256) void k_prep(
    const int* __restrict__ mask, const float* __restrict__ spat,
    const float* __restrict__ x, const float* __restrict__ wq,
    const float* __restrict__ wo,
    u16* __restrict__ biasF,
    u16* __restrict__ xh, u16* __restrict__ xl,
    u16* __restrict__ wqh, u16* __restrict__ wql,
    u16* __restrict__ woh, u16* __restrict__ wol)
{
  __shared__ __align__(16) u16 LB[8192];   // 16 KB fp16 tile

  const int tid = threadIdx.x;
  if (blockIdx.x < 2048) {
    const int blk = blockIdx.x;
    const int ch = blk & 3;              // 512-col chunk
    const int qt = (blk >> 2) & 127;
    const int b  = blk >> 9;
    const float NB = -10000.0f;

    // ---- batched loads: ALL 16 issued before the keep-alive fence ----
    int4   m[8];
    float4 s[8];
#pragma unroll
    for (int rep = 0; rep < 8; ++rep) {
      const int i4 = rep * 256 + tid;            // [0, 2048)
      const int row = i4 >> 7;                   // [0,16)
      const int colc = i4 & 127;                 // int4 within row
      const int gidx = (b * N_ + qt * 16 + row) * N_ + ch * 512 + colc * 4;
      m[rep] = *(const int4*)&mask[gidx];
      s[rep] = *(const float4*)&spat[gidx];
    }
    // IR-proof fence: one asm consumes a component of every loaded vector,
    // so every load must complete before this point; none can be sunk.
    asm volatile("" ::
        "v"(m[0].x), "v"(m[1].x), "v"(m[2].x), "v"(m[3].x),
        "v"(m[4].x), "v"(m[5].x), "v"(m[6].x), "v"(m[7].x),
        "v"(s[0].x), "v"(s[1].x), "v"(s[2].x), "v"(s[3].x),
        "v"(s[4].x), "v"(s[5].x), "v"(s[6].x), "v"(s[7].x));
    __builtin_amdgcn_sched_barrier(0);

    // ---- convert + dense LDS stores ----
#pragma unroll
    for (int rep = 0; rep < 8; ++rep) {
      const int i4 = rep * 256 + tid;
      const int row = i4 >> 7;
      const int colc = i4 & 127;
      u32 w0 = (u32)f2h(m[rep].x ? s[rep].x * LOG2E : NB)
             | ((u32)f2h(m[rep].y ? s[rep].y * LOG2E : NB) << 16);
      u32 w1 = (u32)f2h(m[rep].z ? s[rep].z * LOG2E : NB)
             | ((u32)f2h(m[rep].w ? s[rep].w * LOG2E : NB) << 16);
      const int ktl = colc >> 3, j = (colc >> 2) & 1, hb = colc & 3;
      const int A = (row * 1024 + ktl * 64 + hb * 16 + j * 8)
                  ^ ((row & 1) << 6);            // byte offset, 8B-aligned
      uint2 wv; wv.x = w0; wv.y = w1;
      *(uint2*)&LB[A >> 1] = wv;
    }
    __syncthreads();

    // ---- writer: 4 records/thread, b128 LDS gather + coalesced store ----
    const size_t rbase = ((size_t)(b * 128 + qt) * 64 + ch * 16) * 64;
#pragma unroll
    for (int rep = 0; rep < 4; ++rep) {
      const int o = rep * 256 + tid;             // [0, 1024)
      const int ktl = o >> 6, lane2 = o & 63;
      const int ln2 = lane2 & 15, hb2 = lane2 >> 4;
      const int A = (ln2 * 1024 + ktl * 64 + hb2 * 16) ^ ((ln2 & 1) << 6);
      const short8 v = *(const short8*)&LB[A >> 1];
      *(short8*)&biasF[(rbase + o) * 8] = v;
    }
    return;
  }

  const int NX4 = (M_ * DIMX) / 4;  // 524288
  const int NWQ = 768 * 256;        // 196608
  const int NWO = 256 * 256;        // 65536
  int i = (blockIdx.x - 2048) * 256 + tid;
  if (i < NX4) {
    const float4 v = ((const float4*)x)[i];
    u16v4 hv, lv;
    split2(v.x, &hv.a, &lv.a);
    split2(v.y, &hv.b, &lv.b);
    split2(v.z, &hv.c, &lv.c);
    split2(v.w, &hv.d, &lv.d);
    ((u16v4*)xh)[i] = hv;
    ((u16v4*)xl)[i] = lv;
  } else if (i < NX4 + NWQ) {
    int j = i - NX4;
    int c = j >> 8, k = j & 255;            // out layout [c][k]
    split2(wq[k * 768 + c], &wqh[j], &wql[j]);
  } else if (i < NX4 + NWQ + NWO) {
    int j = i - NX4 - NWQ;
    int c = j >> 8, k = j & 255;
    split2(wo[k * 256 + c], &woh[j], &wol[j]);
  }
}

// ---------------------------------------------------------------------------
// Kernel 2: QKV GEMM, LDS-staged. M=8192, N=768, K=256. grid (12, 64).
// B tile (hi+lo) staged once in 64KB LDS, XOR-swizzled; 2 M-subtiles/block;
// 16 A loads upfront per subtile; MFMA fed from LDS.
// ---------------------------------------------------------------------------
__global__ __launch_bounds__(256) void k_qkv(
    const u16* __restrict__ xh, const u16* __restrict__ xl,
    const u16* __restrict__ wh, const u16* __restrict__ wl,
    u16* __restrict__ qh, u16* __restrict__ ql,
    u16* __restrict__ kf, u16* __restrict__ vf)
{
  __shared__ __align__(16) u16 BhL[64 * 256];   // 32 KB, swizzled
  __shared__ __align__(16) u16 BlL[64 * 256];   // 32 KB

  const int tid = threadIdx.x;
  const int w = tid >> 6, lane = tid & 63;
  const int ln = lane & 15, hb = lane >> 4;
  const int colb = blockIdx.x * 64;

  // ---- stage B (hi+lo) into LDS, reg-batched, coalesced ----
  {
    short8 sb[16];
#pragma unroll
    for (int it = 0; it < 8; ++it) {
      const int c = it * 8 + (tid >> 5), k8 = tid & 31;
      sb[it]     = *(const short8*)&wh[(colb + c) * 256 + k8 * 8];
      sb[8 + it] = *(const short8*)&wl[(colb + c) * 256 + k8 * 8];
    }
#pragma unroll
    for (int it = 0; it < 8; ++it) {
      const int c = it * 8 + (tid >> 5), k8 = tid & 31;
      const int le = c * 256 + ((k8 * 8) ^ ((c & 7) << 3));
      *(short8*)&BhL[le] = sb[it];
      *(short8*)&BlL[le] = sb[8 + it];
    }
  }
  __syncthreads();

#pragma unroll
  for (int st = 0; st < 2; ++st) {
    const int mtile = blockIdx.y * 2 + st;
    const int arow = mtile * 64 + w * 16 + ln;

    short8 a_h8[8], a_l8[8];
#pragma unroll
    for (int ks = 0; ks < 8; ++ks) {
      a_h8[ks] = *(const short8*)&xh[arow * 256 + ks * 32 + hb * 8];
      a_l8[ks] = *(const short8*)&xl[arow * 256 + ks * 32 + hb * 8];
    }

    f32x4 acc[4] = {};
#pragma unroll
    for (int ks = 0; ks < 8; ++ks) {
      const int k0 = ks * 32 + hb * 8;
#pragma unroll
      for (int j = 0; j < 4; ++j) {
        const int c = j * 16 + ln;
        const int le = c * 256 + (k0 ^ ((c & 7) << 3));
        const short8 b_h = *(const short8*)&BhL[le];
        const short8 b_l = *(const short8*)&BlL[le];
        acc[j] = MFMA16(a_h8[ks], b_h, acc[j]);
        acc[j] = MFMA16(a_l8[ks], b_h, acc[j]);
        acc[j] = MFMA16(a_h8[ks], b_l, acc[j]);
      }
    }

    const int mbase = mtile * 64 + w * 16 + hb * 4;
#pragma unroll
    for (int j = 0; j < 4; ++j) {
      const int c = colb + j * 16 + ln;
      const int which = c >> 8;        // 0=q 1=k 2=v
      const int hd = c & 255;
      const int hh = hd >> 6, d = hd & 63;
#pragma unroll
      for (int r = 0; r < 4; ++r) {
        const int m = mbase + r;
        const int bb = m >> 11, nn = m & 2047;
        const int bh = bb * H_ + hh;
        float v = acc[j][r];
        if (which == 0) {
          const int off = (bh * N_ + nn) * DH_ + d;
          v *= (0.125f * LOG2E);                 // scale + exp2-domain fold
          split2(v, &qh[off], &ql[off]);
        } else if (which == 1) {
          const int ktile = nn >> 5, jj = (nn >> 4) & 1, lnn = nn & 15;
          const int kc = d >> 5, hbb = (d >> 3) & 3, e = d & 7;
          const int off = (bh * 64 + ktile) * 2048 + (kc * 2 + jj) * 512
                        + (hbb * 16 + lnn) * 8 + e;
          kf[off] = f2bf(v);
        } else {
          const int ktile = nn >> 5, hbb = (nn >> 3) & 3, e = nn & 7;
          const int j2 = d >> 4, lnn = d & 15;
          const int off = (bh * 64 + ktile) * 2048 + j2 * 512
                        + (hbb * 16 + lnn) * 8 + e;
          vf[off] = f2bf(v);
        }
      }
    }
  }
}

// ---------------------------------------------------------------------------
// Kernel 3: flash attention partials, KV-split=2, BARRIER-FREE (R12 verbatim,
// best measured 54.4us). grid 1024: bid -> half=bid&1, bh=(bid>>1)&15,
// qq=bid>>5. 4 waves = 4 q-tiles of SAME (b,h,half): K/V fragments read
// per-wave directly from global (4x redundancy L1-absorbed). K reg-dbuf one
// tile ahead; V issue-early/use-late; bias fp16 acc-init. Swapped PV:
// O[d][q], q=ln lane-local rescale/l. LDS = per-wave Pbuf only.
// ---------------------------------------------------------------------------
__global__ __launch_bounds__(256, 4) void k_attn(
    const u16* __restrict__ qhg, const u16* __restrict__ qlg,
    const u16* __restrict__ kfg, const u16* __restrict__ vfg,
    const u16* __restrict__ biasF,
    float* __restrict__ Op0, float* __restrict__ Op1,
    float* __restrict__ MP, float* __restrict__ LP)
{
  __shared__ __align__(16) u32 Pbuf[4][320];   // 5 KB: per-wave P exchange

  const int bid = blockIdx.x;
  const int half = bid & 1;
  const int bh = (bid >> 1) & 15;
  const int qq = bid >> 5;
  const int b = bh >> 2, h = bh & 3;
  const int kt0 = half * 32;

  const int tid = threadIdx.x;
  const int w = tid >> 6, lane = tid & 63;
  const int qt = qq * 4 + w;                   // this wave's q-tile [0,128)
  const int ln = lane & 15, hb = lane >> 4;

  // ---- Q fragments (pre-scaled by 0.125*log2e), hi/lo ----
  short8 qfh[2], qfl[2];
  {
    const int base = ((b * H_ + h) * N_ + qt * 16 + ln) * DH_;
    qfh[0] = *(const short8*)&qhg[base + hb * 8];
    qfh[1] = *(const short8*)&qhg[base + 32 + hb * 8];
    qfl[0] = *(const short8*)&qlg[base + hb * 8];
    qfl[1] = *(const short8*)&qlg[base + 32 + hb * 8];
  }

  // per-lane fragment bases (lane*8 folded in; per-tile offset = kt*2048)
  const u16* Kt0 = kfg + (size_t)((b * H_ + h) * 64) * 2048 + lane * 8;
  const u16* Vt0 = vfg + (size_t)((b * H_ + h) * 64) * 2048 + lane * 8;
  const u16* Bt0 = biasF + (size_t)((b * 128 + qt) * 64) * 512 + lane * 8;

  short8 ones;
#pragma unroll
  for (int i = 0; i < 8; ++i) ones[i] = (short)0x3F80;   // bf16 1.0

  f32x4 O[4] = {};        // lane holds O[d=j2*16+hb*4+r][q=ln]
  f32x4 l_acc = {};       // all entries = l(q=ln)
  float m_run = NEGINF;   // per-lane (q=ln)
  u32* Pw = &Pbuf[w][0];

  short8 Ka[4], Kb[4], bc, bn;

  // ---- prologue: K tile kt0 + bias kt0 ----
#pragma unroll
  for (int i = 0; i < 4; ++i)
    Ka[i] = *(const short8*)&Kt0[kt0 * 2048 + i * 512];
  bc = *(const short8*)&Bt0[kt0 * 512];

  auto body = [&](short8 (&Kc)[4], short8 (&Kn)[4],
                  short8& bcur, short8& bnxt, int ktc, int ktn) {
    // ---- issue loads: V for THIS tile (used late), K+bias for NEXT ----
    short8 Vc[4];
#pragma unroll
    for (int i = 0; i < 4; ++i)
      Vc[i] = *(const short8*)&Vt0[ktc * 2048 + i * 512];
#pragma unroll
    for (int i = 0; i < 4; ++i)
      Kn[i] = *(const short8*)&Kt0[ktn * 2048 + i * 512];
    bnxt = *(const short8*)&Bt0[ktn * 512];

    // ---- swapped QK^T, accumulator init = bias ----
    f32x4 dots[2];
#pragma unroll
    for (int j = 0; j < 2; ++j)
#pragma unroll
      for (int r = 0; r < 4; ++r)
        dots[j][r] = (float)__builtin_bit_cast(_Float16, (u16)bcur[j * 4 + r]);
    __builtin_amdgcn_s_setprio(1);
#pragma unroll
    for (int kc = 0; kc < 2; ++kc)
#pragma unroll
      for (int j = 0; j < 2; ++j) {
        dots[j] = MFMA16(Kc[kc * 2 + j], qfh[kc], dots[j]);
        dots[j] = MFMA16(Kc[kc * 2 + j], qfl[kc], dots[j]);
      }
    __builtin_amdgcn_s_setprio(0);

    // ---- per-q online softmax (q=ln), defer-max THR=8 ----
    float pmax = fmaxf(fmaxf(fmaxf(dots[0][0], dots[0][1]),
                             fmaxf(dots[0][2], dots[0][3])),
                       fmaxf(fmaxf(dots[1][0], dots[1][1]),
                             fmaxf(dots[1][2], dots[1][3])));
    pmax = fmaxf(pmax, __shfl_xor(pmax, 16));
    pmax = fmaxf(pmax, __shfl_xor(pmax, 32));
    if (__any(pmax > m_run + DEFER_THR)) {
      const float mn = fmaxf(m_run, pmax);
      const float fac = exp2f(m_run - mn);     // lane-local (q=ln)
      m_run = mn;
#pragma unroll
      for (int j2 = 0; j2 < 4; ++j2) {
        O[j2][0] *= fac; O[j2][1] *= fac; O[j2][2] *= fac; O[j2][3] *= fac;
      }
      l_acc[0] *= fac; l_acc[1] *= fac; l_acc[2] *= fac; l_acc[3] *= fac;
    }
    float p[2][4];
#pragma unroll
    for (int j = 0; j < 2; ++j)
#pragma unroll
      for (int r = 0; r < 4; ++r)
        p[j][r] = exp2f(dots[j][r] - m_run);

    // ---- P-exchange via per-wave LDS (wave-synchronous, no barrier) ----
#pragma unroll
    for (int j = 0; j < 2; ++j) {
      uint2 wv;
      wv.x = cvtpk(p[j][0], p[j][1]);
      wv.y = cvtpk(p[j][2], p[j][3]);
      *(uint2*)&Pw[ln * 20 + j * 8 + hb * 2] = wv;   // k = j*16+hb*4+{0..3}
    }
    const short8 pf = *(const short8*)&Pw[ln * 20 + hb * 4];

    // ---- swapped PV: O += V^T_A x P_B ; l += ones x P ----
    __builtin_amdgcn_s_setprio(1);
#pragma unroll
    for (int j2 = 0; j2 < 4; ++j2)
      O[j2] = MFMA16(Vc[j2], pf, O[j2]);
    l_acc = MFMA16(ones, pf, l_acc);
    __builtin_amdgcn_s_setprio(0);
  };

  for (int it = 0; it < 16; ++it) {
    const int t  = kt0 + 2 * it;
    const int t2 = kt0 + ((2 * it + 2) & 31);  // wraps on last prefetch
    body(Ka, Kb, bc, bn, t,     t + 1);
    body(Kb, Ka, bn, bc, t + 1, t2);
  }

  // ---- epilogue: write unnormalized partial O + per-q m,l ----
  const int gg = (b * H_ + h) * 128 + qt;          // [0, 2048)
  const int g  = gg * 2 + half;                    // MP/LP index
  float* Opg = (half ? Op1 : Op0) + (size_t)gg * 1024;
#pragma unroll
  for (int j2 = 0; j2 < 4; ++j2)
    *(f32x4*)&Opg[ln * 64 + j2 * 16 + hb * 4] = O[j2];
  if (hb == 0) {
    MP[g * 16 + ln] = m_run;
    LP[g * 16 + ln] = l_acc[0];
  }
}

// ---------------------------------------------------------------------------
// Kernel 4 (fused comb+out): out = merge(Op0,Op1;MP,LP) @ Wout + b_out.
// grid (4,64): colb = bx*64; 2 M-subtiles/block; B hi+lo in 64KB LDS.
// A-fragments: merged = (Op0*f1 + Op1*f2)/l per head, split bf16 in-register.
// ---------------------------------------------------------------------------
__global__ __launch_bounds__(256) void k_out(
    const float* __restrict__ Op0, const float* __restrict__ Op1,
    const float* __restrict__ MP, const float* __restrict__ LP,
    const u16* __restrict__ wh, const u16* __restrict__ wl,
    const float* __restrict__ bout, float* __restrict__ out)
{
  __shared__ __align__(16) u16 BhL[64 * 256];   // 32 KB, swizzled
  __shared__ __align__(16) u16 BlL[64 * 256];   // 32 KB

  const int tid = threadIdx.x;
  const int w = tid >> 6, lane = tid & 63;
  const int ln = lane & 15, hb = lane >> 4;
  const int colb = blockIdx.x * 64;

  // ---- stage B (hi+lo) into LDS ----
  {
    short8 sb[16];
#pragma unroll
    for (int it = 0; it < 8; ++it) {
      const int c = it * 8 + (tid >> 5), k8 = tid & 31;
      sb[it]     = *(const short8*)&wh[(colb + c) * 256 + k8 * 8];
      sb[8 + it] = *(const short8*)&wl[(colb + c) * 256 + k8 * 8];
    }
#pragma unroll
    for (int it = 0; it < 8; ++it) {
      const int c = it * 8 + (tid >> 5), k8 = tid & 31;
      const int le = c * 256 + ((k8 * 8) ^ ((c & 7) << 3));
      *(short8*)&BhL[le] = sb[it];
      *(short8*)&BlL[le] = sb[8 + it];
    }
  }
  __syncthreads();

#pragma unroll
  for (int st = 0; st < 2; ++st) {
    const int mtile = blockIdx.y * 2 + st;
    const int arow = mtile * 64 + w * 16 + ln;
    const int bb = arow >> 11, nn = arow & 2047;
    const int qt = nn >> 4, q = nn & 15;

    // ---- per-head merge factors (fo1 = f1/l, fo2 = f2/l) ----
    float fo1[4], fo2[4];
    int ggh[4];
#pragma unroll
    for (int hh = 0; hh < 4; ++hh) {
      const int gg = (bb * H_ + hh) * 128 + qt;
      ggh[hh] = gg;
      const float m1 = MP[gg * 32 + q],      m2 = MP[gg * 32 + 16 + q];
      const float l1 = LP[gg * 32 + q],      l2 = LP[gg * 32 + 16 + q];
      const float mm = fmaxf(m1, m2);
      const float f1 = exp2f(m1 - mm), f2 = exp2f(m2 - mm);
      const float inv = 1.0f / (l1 * f1 + l2 * f2);
      fo1[hh] = f1 * inv;
      fo2[hh] = f2 * inv;
    }

    // ---- build merged A-fragments (bf16 hi/lo) from Op0/Op1 ----
    short8 a_h8[8], a_l8[8];
#pragma unroll
    for (int ks = 0; ks < 8; ++ks) {
      const int hh = ks >> 1;                    // head of this k-chunk
      const int d0 = (ks & 1) * 32 + hb * 8;
      const size_t base = (size_t)ggh[hh] * 1024 + q * 64 + d0;
      const f32x4 u0 = *(const f32x4*)&Op0[base];
      const f32x4 u1 = *(const f32x4*)&Op0[base + 4];
      const f32x4 v0 = *(const f32x4*)&Op1[base];
      const f32x4 v1 = *(const f32x4*)&Op1[base + 4];
#pragma unroll
      for (int e = 0; e < 4; ++e) {
        const float mv = u0[e] * fo1[hh] + v0[e] * fo2[hh];
        const u16 hbits = f2bf(mv);
        a_h8[ks][e] = (short)hbits;
        a_l8[ks][e] = (short)f2bf(mv - bf2f(hbits));
      }
#pragma unroll
      for (int e = 0; e < 4; ++e) {
        const float mv = u1[e] * fo1[hh] + v1[e] * fo2[hh];
        const u16 hbits = f2bf(mv);
        a_h8[ks][e + 4] = (short)hbits;
        a_l8[ks][e + 4] = (short)f2bf(mv - bf2f(hbits));
      }
    }

    f32x4 acc[4] = {};
#pragma unroll
    for (int ks = 0; ks < 8; ++ks) {
      const int k0 = ks * 32 + hb * 8;
#pragma unroll
      for (int j = 0; j < 4; ++j) {
        const int c = j * 16 + ln;
        const int le = c * 256 + (k0 ^ ((c & 7) << 3));
        const short8 b_h = *(const short8*)&BhL[le];
        const short8 b_l = *(const short8*)&BlL[le];
        acc[j] = MFMA16(a_h8[ks], b_h, acc[j]);
        acc[j] = MFMA16(a_l8[ks], b_h, acc[j]);
        acc[j] = MFMA16(a_h8[ks], b_l, acc[j]);
      }
    }

    const int mbase = mtile * 64 + w * 16 + hb * 4;
#pragma unroll
    for (int j = 0; j < 4; ++j) {
      const int c = colb + j * 16 + ln;
      const float bbv = bout[c];
#pragma unroll
      for (int r = 0; r < 4; ++r)
        out[(mbase + r) * 256 + c] = acc[j][r] + bbv;
    }
  }
}

// ---------------------------------------------------------------------------
extern "C" void kernel_launch(void* const* d_in, const int* in_sizes, int n_in,
                              void* d_out, int out_size, void* d_ws, size_t ws_size,
                              hipStream_t stream)
{
  (void)in_sizes; (void)n_in; (void)out_size; (void)ws_size;
  const float* x    = (const float*)d_in[0];
  const int*   mask = (const int*)d_in[1];
  const float* spat = (const float*)d_in[2];
  const float* wq   = (const float*)d_in[3];
  const float* wo   = (const float*)d_in[4];
  const float* bout = (const float*)d_in[5];
  float* out = (float*)d_out;

  char* ws = (char*)d_ws;
  size_t o = 0;
  auto alloc = [&](size_t bytes) -> char* {
    char* p = ws + o;
    o += (bytes + 255) & ~(size_t)255;
    return p;
  };
  u16* xh  = (u16*)alloc((size_t)M_ * 256 * 2);   // 4 MB  \ Op0 alias (8 MB)
  u16* xl  = (u16*)alloc((size_t)M_ * 256 * 2);   // 4 MB  /
  u16* wqh = (u16*)alloc((size_t)768 * 256 * 2);  // 384KB -> MP alias (256KB)
  u16* wql = (u16*)alloc((size_t)768 * 256 * 2);  // 384KB -> LP alias (256KB)
  u16* woh = (u16*)alloc((size_t)256 * 256 * 2);
  u16* wol = (u16*)alloc((size_t)256 * 256 * 2);
  u16* qh  = (u16*)alloc((size_t)16 * N_ * DH_ * 2);
  u16* ql  = (u16*)alloc((size_t)16 * N_ * DH_ * 2);
  u16* kf  = (u16*)alloc((size_t)16 * N_ * DH_ * 2);
  u16* vf  = (u16*)alloc((size_t)16 * N_ * DH_ * 2);
  u16* biasF = (u16*)alloc((size_t)4 * 128 * 64 * 512 * 2);  // 33.5 MB fp16
  float* Op1 = (float*)alloc((size_t)2048 * 1024 * 4);       // 8 MB fresh

  // Aliases (dead by the time they're written, R9-proven pattern):
  //  Op0 (8,388,608 B) <- xh+xl (contiguous, dead after k_qkv)
  //  MP/LP (262,144 B) <- wqh / wql (393,216 B each, dead after k_qkv)
  float* Op0 = (float*)xh;
  float* MP  = (float*)wqh;
  float* LP  = (float*)wql;

  hipLaunchKernelGGL(k_prep, dim3(5120), dim3(256), 0, stream,
                     mask, spat, x, wq, wo, biasF,
                     xh, xl, wqh, wql, woh, wol);
  hipLaunchKernelGGL(k_qkv, dim3(12, 64), dim3(256), 0, stream,
                     xh, xl, wqh, wql, qh, ql, kf, vf);
  hipLaunchKernelGGL(k_attn, dim3(1024), dim3(256), 0, stream,
                     qh, ql, kf, vf, biasF, Op0, Op1, MP, LP);
  hipLaunchKernelGGL(k_out, dim3(4, 64), dim3(256), 0, stream,
                     Op0, Op1, MP, LP, woh, wol, bout, out);
}

// Round 22
// 117.511 us; speedup vs baseline: 1.0312x; 1.0209x over previous
//
#include <hip/hip_runtime.h>

// ============================================================================
// AttentionWithSpatial: x@Wqkv -> masked/biased 4-head attention -> @Wout+b
// b=4, n=2048, dim=256, heads=4, dhead=64, scale=0.125
//
// R21 post-mortem: k_prep pinned ~58 across 3 mechanisms (dense loads,
// batching, fences) -- in-flight-bytes theory falsified by arithmetic; stop.
// R22 = final assembly of best-measured parts (never run together):
//  - k_prep/k_qkv/k_attn verbatim from R14 (best wall, 115.06us):
//    bias 2-rec prefuse + split; LDS-staged QKV GEMM; QBLK=32 barrier-free
//    attention (grid 512, Q hi-only, swapped PV, defer-max).
//  - k_out = fused 2-way flash merge + output GEMM (R16, proven, layout-
//    compatible with R14's epilogue). k_comb eliminated. Op1 fresh 8MB.
// ============================================================================

#define B_   4
#define N_   2048
#define H_   4
#define DH_  64
#define DIMX 256
#define M_   (B_*N_)   // 8192

#define LOG2E  1.4426950408889634f
#define NEGINF (-1e30f)
#define DEFER_THR 8.0f

typedef __attribute__((ext_vector_type(8))) short short8;
typedef __attribute__((ext_vector_type(4))) float f32x4;
typedef unsigned short u16;
typedef unsigned int   u32;

#define MFMA16(a,b,c) __builtin_amdgcn_mfma_f32_16x16x32_bf16((a),(b),(c),0,0,0)

__device__ __forceinline__ u16 f2bf(float f) {
  u32 u = __builtin_bit_cast(u32, f);
  u += 0x7fffu + ((u >> 16) & 1u);   // RNE
  return (u16)(u >> 16);
}
__device__ __forceinline__ float bf2f(u16 h) {
  u32 u = ((u32)h) << 16;
  return __builtin_bit_cast(float, u);
}
__device__ __forceinline__ void split2(float f, u16* hi, u16* lo) {
  u16 h = f2bf(f);
  *hi = h;
  *lo = f2bf(f - bf2f(h));
}
__device__ __forceinline__ u32 cvtpk(float lo, float hi) {
  u32 r;
  asm("v_cvt_pk_bf16_f32 %0, %1, %2" : "=v"(r) : "v"(lo), "v"(hi));
  return r;
}

struct u16v4 { u16 a, b, c, d; };
struct u16v8 { u16 v[8]; };

// ---------------------------------------------------------------------------
// Kernel 1 (fused prep, NO LDS):
//  blocks [0,4096): bias prefuse, TWO adjacent-kt records per thread
//  blocks [4096,7168): x -> xh/xl split; Wqkv/Wout transpose+split
// ---------------------------------------------------------------------------
__global__ __launch_bounds__(256) void k_prep(
    const int* __restrict__ mask, const float* __restrict__ spat,
    const float* __restrict__ x, const float* __restrict__ wq,
    const float* __restrict__ wo,
    u16* __restrict__ biasF,
    u16* __restrict__ xh, u16* __restrict__ xl,
    u16* __restrict__ wqh, u16* __restrict__ wql,
    u16* __restrict__ woh, u16* __restrict__ wol)
{
  if (blockIdx.x < 4096) {
    const int rr = blockIdx.x * 256 + threadIdx.x;    // [0, 1048576)
    const int lane = rr & 63;
    const int kt2 = (rr >> 6) & 31;                   // kt pair
    const int qt = (rr >> 11) & 127;
    const int b  = rr >> 18;
    const int kt = kt2 * 2;
    const int ln = lane & 15, hb = lane >> 4;
    const int q  = qt * 16 + ln;
    const int c0 = kt * 32 + hb * 4;
    const int base = (b * N_ + q) * N_ + c0;

    int4   m[4];
    float4 s[4];
#pragma unroll
    for (int i = 0; i < 4; ++i) {
      m[i] = *(const int4*)&mask[base + i * 16];
      s[i] = *(const float4*)&spat[base + i * 16];
    }

    const float NB = -10000.0f;
    const size_t r0 = ((size_t)((b * 128 + qt) * 64 + kt) * 64 + lane) * 8;
#pragma unroll
    for (int g = 0; g < 2; ++g) {      // record kt+g
      u16v8 o;
      const int4   ma = m[g * 2], mb = m[g * 2 + 1];
      const float4 sa = s[g * 2], sb = s[g * 2 + 1];
      o.v[0] = __builtin_bit_cast(u16, (_Float16)(ma.x ? sa.x * LOG2E : NB));
      o.v[1] = __builtin_bit_cast(u16, (_Float16)(ma.y ? sa.y * LOG2E : NB));
      o.v[2] = __builtin_bit_cast(u16, (_Float16)(ma.z ? sa.z * LOG2E : NB));
      o.v[3] = __builtin_bit_cast(u16, (_Float16)(ma.w ? sa.w * LOG2E : NB));
      o.v[4] = __builtin_bit_cast(u16, (_Float16)(mb.x ? sb.x * LOG2E : NB));
      o.v[5] = __builtin_bit_cast(u16, (_Float16)(mb.y ? sb.y * LOG2E : NB));
      o.v[6] = __builtin_bit_cast(u16, (_Float16)(mb.z ? sb.z * LOG2E : NB));
      o.v[7] = __builtin_bit_cast(u16, (_Float16)(mb.w ? sb.w * LOG2E : NB));
      *(u16v8*)&biasF[r0 + (size_t)g * 512] = o;
    }
    return;
  }

  const int NX4 = (M_ * DIMX) / 4;  // 524288
  const int NWQ = 768 * 256;        // 196608
  const int NWO = 256 * 256;        // 65536
  int i = (blockIdx.x - 4096) * 256 + threadIdx.x;
  if (i < NX4) {
    const float4 v = ((const float4*)x)[i];
    u16v4 hv, lv;
    split2(v.x, &hv.a, &lv.a);
    split2(v.y, &hv.b, &lv.b);
    split2(v.z, &hv.c, &lv.c);
    split2(v.w, &hv.d, &lv.d);
    ((u16v4*)xh)[i] = hv;
    ((u16v4*)xl)[i] = lv;
  } else if (i < NX4 + NWQ) {
    int j = i - NX4;
    int c = j >> 8, k = j & 255;            // out layout [c][k]
    split2(wq[k * 768 + c], &wqh[j], &wql[j]);
  } else if (i < NX4 + NWQ + NWO) {
    int j = i - NX4 - NWQ;
    int c = j >> 8, k = j & 255;
    split2(wo[k * 256 + c], &woh[j], &wol[j]);
  }
}

// ---------------------------------------------------------------------------
// Kernel 2: QKV GEMM, LDS-staged. M=8192, N=768, K=256. grid (12, 64).
// B tile (hi+lo) staged once in 64KB LDS, XOR-swizzled; 2 M-subtiles/block;
// 16 A loads upfront per subtile; MFMA fed from LDS.
// ---------------------------------------------------------------------------
__global__ __launch_bounds__(256) void k_qkv(
    const u16* __restrict__ xh, const u16* __restrict__ xl,
    const u16* __restrict__ wh, const u16* __restrict__ wl,
    u16* __restrict__ qh, u16* __restrict__ ql,
    u16* __restrict__ kf, u16* __restrict__ vf)
{
  __shared__ __align__(16) u16 BhL[64 * 256];   // 32 KB, swizzled
  __shared__ __align__(16) u16 BlL[64 * 256];   // 32 KB

  const int tid = threadIdx.x;
  const int w = tid >> 6, lane = tid & 63;
  const int ln = lane & 15, hb = lane >> 4;
  const int colb = blockIdx.x * 64;

  // ---- stage B (hi+lo) into LDS, reg-batched, coalesced ----
  {
    short8 sb[16];
#pragma unroll
    for (int it = 0; it < 8; ++it) {
      const int c = it * 8 + (tid >> 5), k8 = tid & 31;
      sb[it]     = *(const short8*)&wh[(colb + c) * 256 + k8 * 8];
      sb[8 + it] = *(const short8*)&wl[(colb + c) * 256 + k8 * 8];
    }
#pragma unroll
    for (int it = 0; it < 8; ++it) {
      const int c = it * 8 + (tid >> 5), k8 = tid & 31;
      const int le = c * 256 + ((k8 * 8) ^ ((c & 7) << 3));
      *(short8*)&BhL[le] = sb[it];
      *(short8*)&BlL[le] = sb[8 + it];
    }
  }
  __syncthreads();

#pragma unroll
  for (int st = 0; st < 2; ++st) {
    const int mtile = blockIdx.y * 2 + st;
    const int arow = mtile * 64 + w * 16 + ln;

    short8 a_h8[8], a_l8[8];
#pragma unroll
    for (int ks = 0; ks < 8; ++ks) {
      a_h8[ks] = *(const short8*)&xh[arow * 256 + ks * 32 + hb * 8];
      a_l8[ks] = *(const short8*)&xl[arow * 256 + ks * 32 + hb * 8];
    }

    f32x4 acc[4] = {};
#pragma unroll
    for (int ks = 0; ks < 8; ++ks) {
      const int k0 = ks * 32 + hb * 8;
#pragma unroll
      for (int j = 0; j < 4; ++j) {
        const int c = j * 16 + ln;
        const int le = c * 256 + (k0 ^ ((c & 7) << 3));
        const short8 b_h = *(const short8*)&BhL[le];
        const short8 b_l = *(const short8*)&BlL[le];
        acc[j] = MFMA16(a_h8[ks], b_h, acc[j]);
        acc[j] = MFMA16(a_l8[ks], b_h, acc[j]);
        acc[j] = MFMA16(a_h8[ks], b_l, acc[j]);
      }
    }

    const int mbase = mtile * 64 + w * 16 + hb * 4;
#pragma unroll
    for (int j = 0; j < 4; ++j) {
      const int c = colb + j * 16 + ln;
      const int which = c >> 8;        // 0=q 1=k 2=v
      const int hd = c & 255;
      const int hh = hd >> 6, d = hd & 63;
#pragma unroll
      for (int r = 0; r < 4; ++r) {
        const int m = mbase + r;
        const int bb = m >> 11, nn = m & 2047;
        const int bh = bb * H_ + hh;
        float v = acc[j][r];
        if (which == 0) {
          const int off = (bh * N_ + nn) * DH_ + d;
          v *= (0.125f * LOG2E);                 // scale + exp2-domain fold
          split2(v, &qh[off], &ql[off]);
        } else if (which == 1) {
          const int ktile = nn >> 5, jj = (nn >> 4) & 1, lnn = nn & 15;
          const int kc = d >> 5, hbb = (d >> 3) & 3, e = d & 7;
          const int off = (bh * 64 + ktile) * 2048 + (kc * 2 + jj) * 512
                        + (hbb * 16 + lnn) * 8 + e;
          kf[off] = f2bf(v);
        } else {
          const int ktile = nn >> 5, hbb = (nn >> 3) & 3, e = nn & 7;
          const int j2 = d >> 4, lnn = d & 15;
          const int off = (bh * 64 + ktile) * 2048 + j2 * 512
                        + (hbb * 16 + lnn) * 8 + e;
          vf[off] = f2bf(v);
        }
      }
    }
  }
}

// ---------------------------------------------------------------------------
// Kernel 3: flash attention partials, KV-split=2, BARRIER-FREE, QBLK=32
// (R14 verbatim). grid 512: bid -> half=bid&1, bh=(bid>>1)&15, qp=bid>>5.
// Wave w handles q-tiles qp*8 + w*2 + {0,1}; each K/V fragment load feeds
// BOTH q-tiles; two independent softmax chains. Q hi-only.
// K reg-dbuf one tile ahead; V issue-early/use-late; bias fp16 acc-init.
// Swapped PV: O[d][q], q=ln lane-local rescale/l. No __syncthreads.
// ---------------------------------------------------------------------------
__global__ __launch_bounds__(256) void k_attn(
    const u16* __restrict__ qhg,
    const u16* __restrict__ kfg, const u16* __restrict__ vfg,
    const u16* __restrict__ biasF,
    float* __restrict__ Op0, float* __restrict__ Op1,
    float* __restrict__ MP, float* __restrict__ LP)
{
  __shared__ __align__(16) u32 Pbuf[4][2][320];   // 10 KB: per-wave, per-qi

  const int bid = blockIdx.x;
  const int half = bid & 1;
  const int bh = (bid >> 1) & 15;
  const int qp = bid >> 5;                     // [0,16)
  const int b = bh >> 2, h = bh & 3;
  const int kt0 = half * 32;

  const int tid = threadIdx.x;
  const int w = tid >> 6, lane = tid & 63;
  const int qt0 = qp * 8 + w * 2;              // q-tiles qt0, qt0+1
  const int ln = lane & 15, hb = lane >> 4;

  // ---- Q hi fragments (pre-scaled by 0.125*log2e), per q-tile ----
  short8 qf[2][2];
#pragma unroll
  for (int qi = 0; qi < 2; ++qi) {
    const int base = ((b * H_ + h) * N_ + (qt0 + qi) * 16 + ln) * DH_;
    qf[qi][0] = *(const short8*)&qhg[base + hb * 8];
    qf[qi][1] = *(const short8*)&qhg[base + 32 + hb * 8];
  }

  // per-lane fragment bases (lane*8 folded; per-tile offset = kt*2048)
  const u16* Kt0 = kfg + (size_t)((b * H_ + h) * 64) * 2048 + lane * 8;
  const u16* Vt0 = vfg + (size_t)((b * H_ + h) * 64) * 2048 + lane * 8;
  const u16* Bt0 = biasF + (size_t)((b * 128 + qt0) * 64) * 512 + lane * 8;
  const u16* Bt1 = Bt0 + (size_t)64 * 512;     // q-tile qt0+1

  short8 ones;
#pragma unroll
  for (int i = 0; i < 8; ++i) ones[i] = (short)0x3F80;   // bf16 1.0

  f32x4 O[2][4] = {};      // lane holds O[qi][d=j2*16+hb*4+r][q=ln]
  f32x4 l_acc[2] = {};     // all entries = l(q=ln)
  float m_run[2] = {NEGINF, NEGINF};

  short8 Ka[4], Kb[4];
  short8 bc[2], bn[2];

  // ---- prologue: K tile kt0 + bias kt0 ----
#pragma unroll
  for (int i = 0; i < 4; ++i)
    Ka[i] = *(const short8*)&Kt0[kt0 * 2048 + i * 512];
  bc[0] = *(const short8*)&Bt0[kt0 * 512];
  bc[1] = *(const short8*)&Bt1[kt0 * 512];

  auto body = [&](short8 (&Kc)[4], short8 (&Kn)[4],
                  short8 (&bcur)[2], short8 (&bnxt)[2], int ktc, int ktn) {
    // ---- issue loads: V for THIS tile (used late), K+bias for NEXT ----
    short8 Vc[4];
#pragma unroll
    for (int i = 0; i < 4; ++i)
      Vc[i] = *(const short8*)&Vt0[ktc * 2048 + i * 512];
#pragma unroll
    for (int i = 0; i < 4; ++i)
      Kn[i] = *(const short8*)&Kt0[ktn * 2048 + i * 512];
    bnxt[0] = *(const short8*)&Bt0[ktn * 512];
    bnxt[1] = *(const short8*)&Bt1[ktn * 512];

#pragma unroll
    for (int qi = 0; qi < 2; ++qi) {
      // ---- swapped QK^T (Q hi only), accumulator init = bias ----
      f32x4 dots[2];
#pragma unroll
      for (int j = 0; j < 2; ++j)
#pragma unroll
        for (int r = 0; r < 4; ++r)
          dots[j][r] =
              (float)__builtin_bit_cast(_Float16, (u16)bcur[qi][j * 4 + r]);
      __builtin_amdgcn_s_setprio(1);
#pragma unroll
      for (int kc = 0; kc < 2; ++kc)
#pragma unroll
        for (int j = 0; j < 2; ++j)
          dots[j] = MFMA16(Kc[kc * 2 + j], qf[qi][kc], dots[j]);
      __builtin_amdgcn_s_setprio(0);

      // ---- per-q online softmax (q=ln), defer-max THR=8 ----
      float pmax = fmaxf(fmaxf(fmaxf(dots[0][0], dots[0][1]),
                               fmaxf(dots[0][2], dots[0][3])),
                         fmaxf(fmaxf(dots[1][0], dots[1][1]),
                               fmaxf(dots[1][2], dots[1][3])));
      pmax = fmaxf(pmax, __shfl_xor(pmax, 16));
      pmax = fmaxf(pmax, __shfl_xor(pmax, 32));
      if (__any(pmax > m_run[qi] + DEFER_THR)) {
        const float mn = fmaxf(m_run[qi], pmax);
        const float fac = exp2f(m_run[qi] - mn);   // lane-local (q=ln)
        m_run[qi] = mn;
#pragma unroll
        for (int j2 = 0; j2 < 4; ++j2) {
          O[qi][j2][0] *= fac; O[qi][j2][1] *= fac;
          O[qi][j2][2] *= fac; O[qi][j2][3] *= fac;
        }
        l_acc[qi][0] *= fac; l_acc[qi][1] *= fac;
        l_acc[qi][2] *= fac; l_acc[qi][3] *= fac;
      }
      float p[2][4];
#pragma unroll
      for (int j = 0; j < 2; ++j)
#pragma unroll
        for (int r = 0; r < 4; ++r)
          p[j][r] = exp2f(dots[j][r] - m_run[qi]);

      // ---- P-exchange via per-wave LDS (wave-synchronous) ----
      u32* Pw = &Pbuf[w][qi][0];
#pragma unroll
      for (int j = 0; j < 2; ++j) {
        uint2 wv;
        wv.x = cvtpk(p[j][0], p[j][1]);
        wv.y = cvtpk(p[j][2], p[j][3]);
        *(uint2*)&Pw[ln * 20 + j * 8 + hb * 2] = wv;  // k = j*16+hb*4+{0..3}
      }
      const short8 pf = *(const short8*)&Pw[ln * 20 + hb * 4];

      // ---- swapped PV: O += V^T_A x P_B ; l += ones x P ----
      __builtin_amdgcn_s_setprio(1);
#pragma unroll
      for (int j2 = 0; j2 < 4; ++j2)
        O[qi][j2] = MFMA16(Vc[j2], pf, O[qi][j2]);
      l_acc[qi] = MFMA16(ones, pf, l_acc[qi]);
      __builtin_amdgcn_s_setprio(0);
    }
  };

  for (int it = 0; it < 16; ++it) {
    const int t  = kt0 + 2 * it;
    const int t2 = kt0 + ((2 * it + 2) & 31);  // wraps on last prefetch
    body(Ka, Kb, bc, bn, t,     t + 1);
    body(Kb, Ka, bn, bc, t + 1, t2);
  }

  // ---- epilogue: write unnormalized partial O + per-q m,l ----
#pragma unroll
  for (int qi = 0; qi < 2; ++qi) {
    const int gg = (b * H_ + h) * 128 + qt0 + qi;    // [0, 2048)
    const int g  = gg * 2 + half;                    // MP/LP index
    float* Opg = (half ? Op1 : Op0) + (size_t)gg * 1024;
#pragma unroll
    for (int j2 = 0; j2 < 4; ++j2)
      *(f32x4*)&Opg[ln * 64 + j2 * 16 + hb * 4] = O[qi][j2];
    if (hb == 0) {
      MP[g * 16 + ln] = m_run[qi];
      LP[g * 16 + ln] = l_acc[qi][0];
    }
  }
}

// ---------------------------------------------------------------------------
// Kernel 4 (fused comb+out): out = merge(Op0,Op1;MP,LP) @ Wout + b_out.
// grid (4,64): colb = bx*64; 2 M-subtiles/block; B hi+lo in 64KB LDS.
// A-fragments: merged = (Op0*f1 + Op1*f2)/l per head, split bf16 in-register.
// ---------------------------------------------------------------------------
__global__ __launch_bounds__(256) void k_out(
    const float* __restrict__ Op0, const float* __restrict__ Op1,
    const float* __restrict__ MP, const float* __restrict__ LP,
    const u16* __restrict__ wh, const u16* __restrict__ wl,
    const float* __restrict__ bout, float* __restrict__ out)
{
  __shared__ __align__(16) u16 BhL[64 * 256];   // 32 KB, swizzled
  __shared__ __align__(16) u16 BlL[64 * 256];   // 32 KB

  const int tid = threadIdx.x;
  const int w = tid >> 6, lane = tid & 63;
  const int ln = lane & 15, hb = lane >> 4;
  const int colb = blockIdx.x * 64;

  // ---- stage B (hi+lo) into LDS ----
  {
    short8 sb[16];
#pragma unroll
    for (int it = 0; it < 8; ++it) {
      const int c = it * 8 + (tid >> 5), k8 = tid & 31;
      sb[it]     = *(const short8*)&wh[(colb + c) * 256 + k8 * 8];
      sb[8 + it] = *(const short8*)&wl[(colb + c) * 256 + k8 * 8];
    }
#pragma unroll
    for (int it = 0; it < 8; ++it) {
      const int c = it * 8 + (tid >> 5), k8 = tid & 31;
      const int le = c * 256 + ((k8 * 8) ^ ((c & 7) << 3));
      *(short8*)&BhL[le] = sb[it];
      *(short8*)&BlL[le] = sb[8 + it];
    }
  }
  __syncthreads();

#pragma unroll
  for (int st = 0; st < 2; ++st) {
    const int mtile = blockIdx.y * 2 + st;
    const int arow = mtile * 64 + w * 16 + ln;
    const int bb = arow >> 11, nn = arow & 2047;
    const int qt = nn >> 4, q = nn & 15;

    // ---- per-head merge factors (fo1 = f1/l, fo2 = f2/l) ----
    float fo1[4], fo2[4];
    int ggh[4];
#pragma unroll
    for (int hh = 0; hh < 4; ++hh) {
      const int gg = (bb * H_ + hh) * 128 + qt;
      ggh[hh] = gg;
      const float m1 = MP[gg * 32 + q],      m2 = MP[gg * 32 + 16 + q];
      const float l1 = LP[gg * 32 + q],      l2 = LP[gg * 32 + 16 + q];
      const float mm = fmaxf(m1, m2);
      const float f1 = exp2f(m1 - mm), f2 = exp2f(m2 - mm);
      const float inv = 1.0f / (l1 * f1 + l2 * f2);
      fo1[hh] = f1 * inv;
      fo2[hh] = f2 * inv;
    }

    // ---- build merged A-fragments (bf16 hi/lo) from Op0/Op1 ----
    short8 a_h8[8], a_l8[8];
#pragma unroll
    for (int ks = 0; ks < 8; ++ks) {
      const int hh = ks >> 1;                    // head of this k-chunk
      const int d0 = (ks & 1) * 32 + hb * 8;
      const size_t base = (size_t)ggh[hh] * 1024 + q * 64 + d0;
      const f32x4 u0 = *(const f32x4*)&Op0[base];
      const f32x4 u1 = *(const f32x4*)&Op0[base + 4];
      const f32x4 v0 = *(const f32x4*)&Op1[base];
      const f32x4 v1 = *(const f32x4*)&Op1[base + 4];
#pragma unroll
      for (int e = 0; e < 4; ++e) {
        const float mv = u0[e] * fo1[hh] + v0[e] * fo2[hh];
        const u16 hbits = f2bf(mv);
        a_h8[ks][e] = (short)hbits;
        a_l8[ks][e] = (short)f2bf(mv - bf2f(hbits));
      }
#pragma unroll
      for (int e = 0; e < 4; ++e) {
        const float mv = u1[e] * fo1[hh] + v1[e] * fo2[hh];
        const u16 hbits = f2bf(mv);
        a_h8[ks][e + 4] = (short)hbits;
        a_l8[ks][e + 4] = (short)f2bf(mv - bf2f(hbits));
      }
    }

    f32x4 acc[4] = {};
#pragma unroll
    for (int ks = 0; ks < 8; ++ks) {
      const int k0 = ks * 32 + hb * 8;
#pragma unroll
      for (int j = 0; j < 4; ++j) {
        const int c = j * 16 + ln;
        const int le = c * 256 + (k0 ^ ((c & 7) << 3));
        const short8 b_h = *(const short8*)&BhL[le];
        const short8 b_l = *(const short8*)&BlL[le];
        acc[j] = MFMA16(a_h8[ks], b_h, acc[j]);
        acc[j] = MFMA16(a_l8[ks], b_h, acc[j]);
        acc[j] = MFMA16(a_h8[ks], b_l, acc[j]);
      }
    }

    const int mbase = mtile * 64 + w * 16 + hb * 4;
#pragma unroll
    for (int j = 0; j < 4; ++j) {
      const int c = colb + j * 16 + ln;
      const float bbv = bout[c];
#pragma unroll
      for (int r = 0; r < 4; ++r)
        out[(mbase + r) * 256 + c] = acc[j][r] + bbv;
    }
  }
}

// ---------------------------------------------------------------------------
extern "C" void kernel_launch(void* const* d_in, const int* in_sizes, int n_in,
                              void* d_out, int out_size, void* d_ws, size_t ws_size,
                              hipStream_t stream)
{
  (void)in_sizes; (void)n_in; (void)out_size; (void)ws_size;
  const float* x    = (const float*)d_in[0];
  const int*   mask = (const int*)d_in[1];
  const float* spat = (const float*)d_in[2];
  const float* wq   = (const float*)d_in[3];
  const float* wo   = (const float*)d_in[4];
  const float* bout = (const float*)d_in[5];
  float* out = (float*)d_out;

  char* ws = (char*)d_ws;
  size_t o = 0;
  auto alloc = [&](size_t bytes) -> char* {
    char* p = ws + o;
    o += (bytes + 255) & ~(size_t)255;
    return p;
  };
  u16* xh  = (u16*)alloc((size_t)M_ * 256 * 2);   // 4 MB  \ Op0 alias (8 MB)
  u16* xl  = (u16*)alloc((size_t)M_ * 256 * 2);   // 4 MB  /
  u16* wqh = (u16*)alloc((size_t)768 * 256 * 2);  // 384KB -> MP alias (256KB)
  u16* wql = (u16*)alloc((size_t)768 * 256 * 2);  // 384KB -> LP alias (256KB)
  u16* woh = (u16*)alloc((size_t)256 * 256 * 2);
  u16* wol = (u16*)alloc((size_t)256 * 256 * 2);
  u16* qh  = (u16*)alloc((size_t)16 * N_ * DH_ * 2);
  u16* ql  = (u16*)alloc((size_t)16 * N_ * DH_ * 2);
  u16* kf  = (u16*)alloc((size_t)16 * N_ * DH_ * 2);
  u16* vf  = (u16*)alloc((size_t)16 * N_ * DH_ * 2);
  u16* biasF = (u16*)alloc((size_t)4 * 128 * 64 * 512 * 2);  // 33.5 MB fp16
  float* Op1 = (float*)alloc((size_t)2048 * 1024 * 4);       // 8 MB fresh

  // Aliases (dead by the time they're written, R9-proven pattern):
  //  Op0 (8,388,608 B) <- xh+xl (contiguous, dead after k_qkv)
  //  MP/LP (262,144 B) <- wqh / wql (393,216 B each, dead after k_qkv)
  float* Op0 = (float*)xh;
  float* MP  = (float*)wqh;
  float* LP  = (float*)wql;

  hipLaunchKernelGGL(k_prep, dim3(7168), dim3(256), 0, stream,
                     mask, spat, x, wq, wo, biasF,
                     xh, xl, wqh, wql, woh, wol);
  hipLaunchKernelGGL(k_qkv, dim3(12, 64), dim3(256), 0, stream,
                     xh, xl, wqh, wql, qh, ql, kf, vf);
  hipLaunchKernelGGL(k_attn, dim3(512), dim3(256), 0, stream,
                     qh, kf, vf, biasF, Op0, Op1, MP, LP);
  hipLaunchKernelGGL(k_out, dim3(4, 64), dim3(256), 0, stream,
                     Op0, Op1, MP, LP, woh, wol, bout, out);
}